// Round 1
// baseline (100.602 us; speedup 1.0000x reference)
//
#include <hip/hip_runtime.h>

// Problem: B=8, C=21, H=512, W=512 ; gt/pred int32 ; output = scalar f32
// mean over B of  tp / max(tp+fp+fn, 1e-8)
//   valid = gt != 255 ; eq = gt==pred
//   gt_in = 1<=gt<21 ; pred_in = 1<=pred<21
//   tp = sum(eq & gt_in & valid) ; fp = sum(!eq & pred_in & valid)
//   fn = sum(!eq & gt_in & valid)   (per sample)

#define N_CLASSES 21
#define IGNORE_LBL 255
#define BATCH 8

__global__ __launch_bounds__(256) void iou_count_kernel(
    const int* __restrict__ gt, const int* __restrict__ pred,
    unsigned int* __restrict__ counts, int vec_per_sample) {
    const int b = blockIdx.y;
    const int4* __restrict__ g4 =
        reinterpret_cast<const int4*>(gt + (size_t)b * vec_per_sample * 4);
    const int4* __restrict__ p4 =
        reinterpret_cast<const int4*>(pred + (size_t)b * vec_per_sample * 4);

    int tp = 0, fp = 0, fn = 0;
    const int stride = gridDim.x * blockDim.x;
    for (int i = blockIdx.x * blockDim.x + threadIdx.x; i < vec_per_sample; i += stride) {
        int4 g = g4[i];
        int4 p = p4[i];
        int gv[4] = {g.x, g.y, g.z, g.w};
        int pv[4] = {p.x, p.y, p.z, p.w};
#pragma unroll
        for (int k = 0; k < 4; ++k) {
            const int gk = gv[k], pk = pv[k];
            const int valid = (gk != IGNORE_LBL);
            const int eq = (gk == pk);
            const int gin = (gk >= 1) & (gk < N_CLASSES);
            const int pin = (pk >= 1) & (pk < N_CLASSES);
            tp += eq & gin & valid;
            fp += (eq ^ 1) & pin & valid;
            fn += (eq ^ 1) & gin & valid;
        }
    }

    // wave (64-lane) butterfly reduce
#pragma unroll
    for (int off = 32; off > 0; off >>= 1) {
        tp += __shfl_down(tp, off);
        fp += __shfl_down(fp, off);
        fn += __shfl_down(fn, off);
    }

    __shared__ int s_tp[4], s_fp[4], s_fn[4];  // 256 threads = 4 waves
    const int wave = threadIdx.x >> 6;
    const int lane = threadIdx.x & 63;
    if (lane == 0) {
        s_tp[wave] = tp;
        s_fp[wave] = fp;
        s_fn[wave] = fn;
    }
    __syncthreads();
    if (threadIdx.x == 0) {
        int t = 0, f = 0, n = 0;
#pragma unroll
        for (int w = 0; w < 4; ++w) {
            t += s_tp[w];
            f += s_fp[w];
            n += s_fn[w];
        }
        atomicAdd(&counts[b * 3 + 0], (unsigned int)t);
        atomicAdd(&counts[b * 3 + 1], (unsigned int)f);
        atomicAdd(&counts[b * 3 + 2], (unsigned int)n);
    }
}

__global__ void iou_final_kernel(const unsigned int* __restrict__ counts,
                                 float* __restrict__ out) {
    if (threadIdx.x == 0 && blockIdx.x == 0) {
        float s = 0.0f;
#pragma unroll
        for (int b = 0; b < BATCH; ++b) {
            const float tp = (float)counts[b * 3 + 0];
            const float fp = (float)counts[b * 3 + 1];
            const float fn = (float)counts[b * 3 + 2];
            s += tp / fmaxf(tp + fp + fn, 1e-8f);
        }
        out[0] = s / (float)BATCH;
    }
}

extern "C" void kernel_launch(void* const* d_in, const int* in_sizes, int n_in,
                              void* d_out, int out_size, void* d_ws, size_t ws_size,
                              hipStream_t stream) {
    const int* gt = (const int*)d_in[0];
    const int* pred = (const int*)d_in[1];
    float* out = (float*)d_out;
    unsigned int* counts = (unsigned int*)d_ws;  // BATCH * 3 u32

    const int total = in_sizes[0];                 // 8*21*512*512
    const int per_sample = total / BATCH;          // 21*512*512 = 5505024
    const int vec_per_sample = per_sample / 4;     // 1376256 int4 per sample

    hipMemsetAsync(counts, 0, BATCH * 3 * sizeof(unsigned int), stream);

    dim3 grid(256, BATCH, 1);  // 2048 blocks total, grid-stride inside sample
    dim3 block(256, 1, 1);
    iou_count_kernel<<<grid, block, 0, stream>>>(gt, pred, counts, vec_per_sample);
    iou_final_kernel<<<1, 64, 0, stream>>>(counts, out);
}